// Round 15
// baseline (301.386 us; speedup 1.0000x reference)
//
#include <hip/hip_runtime.h>
#include <hip/hip_bf16.h>
#include <stdint.h>

// 2-layer LSTM (H=64) fused over T=336, B=4096, + final linear->sigmoid.
// R14 ANTIPHASE base (best: 278us) + 2-WAY PAIRED reciprocals in the
// stage-parallel nonlin: 16 gate rcp -> 8, 4 cell rcp -> 2 (trans/wave
// 40 -> 30) at +2 muls/pair, no clamps (pairwise products cannot overflow
// at this problem's bounded pre-activations).  Clean A/B on trans cost:
// R13's quad-rcp loss is attributed to its clamps + 4-wide product chains.
//   A:  L0: MFMA(gates0(i));            L1: [h0 reads] nonlin->h1(i-2), write
//   B:  L0: nonlin->h0(i), write;       L1: MFMA(gates1(i-1))

typedef __attribute__((ext_vector_type(8))) short s16x8;
typedef __attribute__((ext_vector_type(4))) short s16x4;
typedef __attribute__((ext_vector_type(4))) float f32x4;

#define MFMA_BF16 __builtin_amdgcn_mfma_f32_16x16x32_bf16
#define LOG2E     1.4426950408889634f
#define TWO_LOG2E 2.8853900817779268f

__device__ __forceinline__ short f2bf(float f) {
    uint32_t u = __builtin_bit_cast(uint32_t, f);
    u += 0x7fffu + ((u >> 16) & 1u);   // round-to-nearest-even
    return (short)(u >> 16);
}

__device__ __forceinline__ s16x4 pack_bf16x4(float a, float b, float c, float d) {
    union { uint32_t u[2]; s16x4 s; } r;
    asm("v_cvt_pk_bf16_f32 %0, %1, %2" : "=v"(r.u[0]) : "v"(a), "v"(b));
    asm("v_cvt_pk_bf16_f32 %0, %1, %2" : "=v"(r.u[1]) : "v"(c), "v"(d));
    return r.s;
}

static __device__ __forceinline__ float fexp2(float t){ return __builtin_amdgcn_exp2f(t); }
static __device__ __forceinline__ float frcp (float t){ return __builtin_amdgcn_rcpf(t); }

// rcp(1 + 2^t) for the final linear stage only
__device__ __forceinline__ float rcp1p2(float t) {
    return frcp(1.0f + fexp2(t));
}

// Stage-parallel LSTM nonlinearity, scaled cell c' = c*2log2e, PAIRED rcps.
// acc[m][r] pre-scaled: i,f,o by -log2e; g by +2log2e.
// sigma pairs (i,f) and (g,o): rr = rcp(da*db); sa = rr*db; sb = rr*da (exact).
// Trans: 16 exp2 + 8 rcp + 4 exp2 + 2 rcp = 30/wave (was 40).
__device__ __forceinline__ f32x4 nonlin_wide(const f32x4 acc[4], f32x4& cs) {
    float e0[4], e1[4], e2[4], e3[4];
    #pragma unroll
    for (int r = 0; r < 4; ++r) {           // 16 independent exp2
        e0[r] = fexp2(acc[0][r]);
        e1[r] = fexp2(acc[1][r]);
        e2[r] = fexp2(acc[2][r]);
        e3[r] = fexp2(acc[3][r]);
    }
    float d0[4], d1[4], d2[4], d3[4];
    #pragma unroll
    for (int r = 0; r < 4; ++r) {
        d0[r] = 1.f + e0[r]; d1[r] = 1.f + e1[r];
        d2[r] = 1.f + e2[r]; d3[r] = 1.f + e3[r];
    }
    float rA[4], rB[4];
    #pragma unroll
    for (int r = 0; r < 4; ++r) {           // 8 independent rcp (paired)
        rA[r] = frcp(d0[r] * d1[r]);
        rB[r] = frcp(d2[r] * d3[r]);
    }
    float ov[4], ec[4];
    #pragma unroll
    for (int r = 0; r < 4; ++r) {           // recover gates, update c, 4 exp2
        float iv = rA[r] * d1[r];           // sigma(i)
        float fv = rA[r] * d0[r];           // sigma(f)
        float gq = rB[r] * d3[r];           // rcp(1+2^tg)
        ov[r]    = rB[r] * d2[r];           // sigma(o)
        float gvs = fmaf(-2.f * TWO_LOG2E, gq, TWO_LOG2E);   // 2log2e*tanh(g)
        cs[r] = fmaf(fv, cs[r], iv * gvs);
        ec[r] = fexp2(cs[r]);
    }
    f32x4 h;
    {   float dg0 = 1.f + ec[0], dg1 = 1.f + ec[1];   // 2 paired cell rcp
        float rg = frcp(dg0 * dg1);
        h[0] = ov[0] * fmaf(-2.f, rg * dg1, 1.f);
        h[1] = ov[1] * fmaf(-2.f, rg * dg0, 1.f); }
    {   float dg2 = 1.f + ec[2], dg3 = 1.f + ec[3];
        float rg = frcp(dg2 * dg3);
        h[2] = ov[2] * fmaf(-2.f, rg * dg3, 1.f);
        h[3] = ov[3] * fmaf(-2.f, rg * dg2, 1.f); }
    return h;
}

__global__ __launch_bounds__(512, 1)
void lstm_fused(const float* __restrict__ x,
                const float* __restrict__ w_ih0, const float* __restrict__ w_hh0,
                const float* __restrict__ b_ih0, const float* __restrict__ b_hh0,
                const float* __restrict__ w_ih1, const float* __restrict__ w_hh1,
                const float* __restrict__ b_ih1, const float* __restrict__ b_hh1,
                const float* __restrict__ w_lin, const float* __restrict__ b_lin,
                float* __restrict__ out)
{
    __shared__ __align__(16) short xs[16 * 512];        // 16 KB x-chunk
    __shared__ __align__(16) short h0s[2][16 * 64];     // h0 double buffer
    __shared__ __align__(16) short h1s[16 * 64];        // h1 single buffer
    __shared__ float red[4][16];

    const int tid  = threadIdx.x;
    const int w    = tid >> 6;       // wave 0..7
    const int role = w >> 2;         // 0 = layer0, 1 = layer1
    const int wl   = w & 3;          // j-slice [16wl, 16wl+16)
    const int l    = tid & 63;
    const int bcol = l & 15;
    const int q    = l >> 4;
    const int b0   = blockIdx.x * 16;

    for (int i = tid; i < 16 * 512; i += 512) xs[i] = 0;
    for (int i = tid; i < 16 * 64; i += 512) {
        h0s[0][i] = 0; h0s[1][i] = 0; h1s[i] = 0;
    }
    __syncthreads();

    // sigma(x)=rcp(1+exp2(-x*log2e)); tanh(x)=1-2*rcp(1+exp2(2x*log2e))
    const float scm[4] = { -LOG2E, -LOG2E, TWO_LOG2E, -LOG2E };

    s16x8 aW[4][4];
    f32x4 bias[4];
    #pragma unroll
    for (int m = 0; m < 4; ++m) {
        const int R = m * 64 + wl * 16 + bcol;
        const float sc = scm[m];
        if (role == 0) {
            #pragma unroll
            for (int r = 0; r < 8; ++r) {
                int k = q * 8 + r;
                aW[m][0][r] = (k < 9) ? f2bf(w_ih0[R * 9 + k] * sc) : (short)0;
            }
            #pragma unroll
            for (int kf = 0; kf < 2; ++kf) {
                const float* p = w_hh0 + R * 64 + kf * 32 + q * 8;
                #pragma unroll
                for (int r = 0; r < 8; ++r) aW[m][1 + kf][r] = f2bf(p[r] * sc);
            }
            #pragma unroll
            for (int r = 0; r < 8; ++r) aW[m][3][r] = 0;
            #pragma unroll
            for (int r = 0; r < 4; ++r) {
                int G = m * 64 + wl * 16 + q * 4 + r;
                bias[m][r] = (b_ih0[G] + b_hh0[G]) * sc;
            }
        } else {
            #pragma unroll
            for (int kf = 0; kf < 4; ++kf) {
                int ks = kf * 32 + q * 8;
                const float* p = (ks < 64) ? (w_ih1 + R * 64 + ks)
                                           : (w_hh1 + R * 64 + (ks - 64));
                #pragma unroll
                for (int r = 0; r < 8; ++r) aW[m][kf][r] = f2bf(p[r] * sc);
            }
            #pragma unroll
            for (int r = 0; r < 4; ++r) {
                int G = m * 64 + wl * 16 + q * 4 + r;
                bias[m][r] = (b_ih1[G] + b_hh1[G]) * sc;
            }
        }
    }

    f32x4 cs = {0.f, 0.f, 0.f, 0.f};     // scaled cell state c*2log2e
    f32x4 hq = {0.f, 0.f, 0.f, 0.f};
    f32x4 accL1[4];                      // L1 pending gates (set in B, used next A)
    #pragma unroll
    for (int m = 0; m < 4; ++m) accL1[m] = (f32x4){0.f, 0.f, 0.f, 0.f};

    const int hrd0 = bcol * 64 + (((q    ) ^ (bcol & 7)) << 3);
    const int hrd1 = bcol * 64 + (((4 + q) ^ (bcol & 7)) << 3);
    const int hwr  = bcol * 64 + (((wl * 2 + (q >> 1)) ^ (bcol & 7)) << 3)
                   + ((q & 1) << 2);
    const int xrd  = bcol * 32 + ((q ^ (bcol & 3)) << 3);

    const int    ld_b = (tid & 255) >> 4, ld_t = tid & 15;
    const float* xrow = x + (size_t)(b0 + ld_b) * (336 * 9) + ld_t * 9;
    const int    xs_wr_base = ld_t * 512 + ld_b * 32;
    const int    xswzw = (ld_b & 3) << 3;

    #pragma unroll 1
    for (int i = 0; i <= 337; ++i) {
        if ((i & 15) == 0 && i < 336) {
            if (tid < 256) {
                const float* xp = xrow + (size_t)i * 9;
                #pragma unroll
                for (int d = 0; d < 9; ++d)
                    xs[(xs_wr_base + d) ^ xswzw] = f2bf(xp[d]);
            }
            __syncthreads();
        }

        // ================= interval A =================
        f32x4 acc0[4];
        s16x8 ba1, bb1;                 // role1's hoisted h0(i-1) frags
        if (role == 0) {
            if (i <= 335) {
                s16x8 bx = *(const s16x8*)&xs[(i & 15) * 512 + xrd];
                const short* h0r = h0s[(i & 1) ^ 1];            // h0(i-1)
                s16x8 ba = *(const s16x8*)&h0r[hrd0];
                s16x8 bb = *(const s16x8*)&h0r[hrd1];
                #pragma unroll
                for (int m = 0; m < 4; ++m) acc0[m] = MFMA_BF16(aW[m][0], bx, bias[m], 0, 0, 0);
                #pragma unroll
                for (int m = 0; m < 4; ++m) acc0[m] = MFMA_BF16(aW[m][1], ba, acc0[m], 0, 0, 0);
                #pragma unroll
                for (int m = 0; m < 4; ++m) acc0[m] = MFMA_BF16(aW[m][2], bb, acc0[m], 0, 0, 0);
            }
        } else {
            if (i >= 1 && i <= 336) {   // hoist: h0(i-1) visible since B_end(i-1)
                const short* h0r = h0s[(i & 1) ^ 1];
                ba1 = *(const s16x8*)&h0r[hrd0];
                bb1 = *(const s16x8*)&h0r[hrd1];
            }
            if (i >= 2) {   // nonlin on gates1(i-2) -> h1(i-2) (hides reads above)
                __builtin_amdgcn_s_setprio(1);
                hq = nonlin_wide(accL1, cs);
                __builtin_amdgcn_s_setprio(0);
                *(s16x4*)&h1s[hwr] = pack_bf16x4(hq[0], hq[1], hq[2], hq[3]);
            }
        }
        __syncthreads();   // B_mid: h1(i-2) visible

        // ================= interval B =================
        if (role == 0) {
            if (i <= 335) {
                __builtin_amdgcn_s_setprio(1);
                hq = nonlin_wide(acc0, cs);
                __builtin_amdgcn_s_setprio(0);
                short* h0w = h0s[i & 1];                        // h0(i)
                *(s16x4*)&h0w[hwr] = pack_bf16x4(hq[0], hq[1], hq[2], hq[3]);
            }
        } else {
            if (i >= 1 && i <= 336) {   // gates1(i-1) from h0(i-1), h1(i-2)
                s16x8 b1a = *(const s16x8*)&h1s[hrd0];
                s16x8 b1b = *(const s16x8*)&h1s[hrd1];
                #pragma unroll
                for (int m = 0; m < 4; ++m) accL1[m] = MFMA_BF16(aW[m][0], ba1, bias[m], 0, 0, 0);
                #pragma unroll
                for (int m = 0; m < 4; ++m) accL1[m] = MFMA_BF16(aW[m][1], bb1, accL1[m], 0, 0, 0);
                #pragma unroll
                for (int m = 0; m < 4; ++m) accL1[m] = MFMA_BF16(aW[m][2], b1a, accL1[m], 0, 0, 0);
                #pragma unroll
                for (int m = 0; m < 4; ++m) accL1[m] = MFMA_BF16(aW[m][3], b1b, accL1[m], 0, 0, 0);
            }
        }
        __syncthreads();   // B_end: h0(i) visible
    }

    // ---- out[b] = sigm(sum_j h1_335[b][j] * w_lin[j] + b_lin) ----
    if (role == 1) {
        float part = hq[0] * w_lin[wl * 16 + q * 4 + 0]
                   + hq[1] * w_lin[wl * 16 + q * 4 + 1]
                   + hq[2] * w_lin[wl * 16 + q * 4 + 2]
                   + hq[3] * w_lin[wl * 16 + q * 4 + 3];
        part += __shfl_xor(part, 16, 64);
        part += __shfl_xor(part, 32, 64);
        if (q == 0) red[wl][bcol] = part;
    }
    __syncthreads();
    if (tid < 16) {
        float s = red[0][tid] + red[1][tid] + red[2][tid] + red[3][tid] + b_lin[0];
        out[b0 + tid] = rcp1p2(-s * LOG2E);
    }
}

extern "C" void kernel_launch(void* const* d_in, const int* in_sizes, int n_in,
                              void* d_out, int out_size, void* d_ws, size_t ws_size,
                              hipStream_t stream) {
    const float* x     = (const float*)d_in[0];
    const float* w_ih0 = (const float*)d_in[1];
    const float* w_hh0 = (const float*)d_in[2];
    const float* b_ih0 = (const float*)d_in[3];
    const float* b_hh0 = (const float*)d_in[4];
    const float* w_ih1 = (const float*)d_in[5];
    const float* w_hh1 = (const float*)d_in[6];
    const float* b_ih1 = (const float*)d_in[7];
    const float* b_hh1 = (const float*)d_in[8];
    const float* w_lin = (const float*)d_in[9];
    const float* b_lin = (const float*)d_in[10];

    lstm_fused<<<dim3(256), dim3(512), 0, stream>>>(
        x, w_ih0, w_hh0, b_ih0, b_hh0,
        w_ih1, w_hh1, b_ih1, b_hh1,
        w_lin, b_lin, (float*)d_out);
}

// Round 16
// 276.540 us; speedup vs baseline: 1.0898x; 1.0898x over previous
//
#include <hip/hip_runtime.h>
#include <hip/hip_bf16.h>
#include <stdint.h>

// 2-layer LSTM (H=64) fused over T=336, B=4096, + final linear->sigmoid.
// R14 ANTIPHASE base (best: 278us) + SPLIT NONLINEARITY:
//  stage-1 (16 gate exp2, ~190cyc trans issue) runs in the PRODUCING interval
//  right after the MFMAs that make the gates -- in that wave's idle slot,
//  hidden under the partner role's nonlin burst.  stage-2 (16 rcp + cell
//  exp2/rcp + c-update) stays in the consuming interval.  sched_barrier(0)
//  pins stage-1 so the compiler cannot sink it across the s_barrier.
//   A:  L0: MFMA(gates0(i)) + s1;        L1: [h0 reads] s2->h1(i-2), write
//   B:  L0: s2->h0(i), write;            L1: MFMA(gates1(i-1)) + s1
// Nonlin math identical to R14 (stage-parallel, scaled cell c'=c*2log2e).

typedef __attribute__((ext_vector_type(8))) short s16x8;
typedef __attribute__((ext_vector_type(4))) short s16x4;
typedef __attribute__((ext_vector_type(4))) float f32x4;

#define MFMA_BF16 __builtin_amdgcn_mfma_f32_16x16x32_bf16
#define LOG2E     1.4426950408889634f
#define TWO_LOG2E 2.8853900817779268f

__device__ __forceinline__ short f2bf(float f) {
    uint32_t u = __builtin_bit_cast(uint32_t, f);
    u += 0x7fffu + ((u >> 16) & 1u);   // round-to-nearest-even
    return (short)(u >> 16);
}

__device__ __forceinline__ s16x4 pack_bf16x4(float a, float b, float c, float d) {
    union { uint32_t u[2]; s16x4 s; } r;
    asm("v_cvt_pk_bf16_f32 %0, %1, %2" : "=v"(r.u[0]) : "v"(a), "v"(b));
    asm("v_cvt_pk_bf16_f32 %0, %1, %2" : "=v"(r.u[1]) : "v"(c), "v"(d));
    return r.s;
}

static __device__ __forceinline__ float fexp2(float t){ return __builtin_amdgcn_exp2f(t); }
static __device__ __forceinline__ float frcp (float t){ return __builtin_amdgcn_rcpf(t); }

// rcp(1 + 2^t) for the final linear stage only
__device__ __forceinline__ float rcp1p2(float t) {
    return frcp(1.0f + fexp2(t));
}

// ---- split nonlinearity (R14 math) ----
// acc[m][r] pre-scaled: i,f,o by -log2e (sigma = rcp(1+2^t)); g by +2log2e.
// stage 1: the 16 gate exp2s (issued in the producing interval).
__device__ __forceinline__ void nl_s1(const f32x4 acc[4], float e[16]) {
    #pragma unroll
    for (int r = 0; r < 4; ++r) {
        e[r]      = fexp2(acc[0][r]);
        e[4 + r]  = fexp2(acc[1][r]);
        e[8 + r]  = fexp2(acc[2][r]);
        e[12 + r] = fexp2(acc[3][r]);
    }
}
// stage 2: 16 rcp, scaled c-update (c' = c*2log2e), 4 cell exp2 + 4 rcp.
__device__ __forceinline__ f32x4 nl_s2(const float e[16], f32x4& cs) {
    float iv[4], fv[4], gq[4], ov[4];
    #pragma unroll
    for (int r = 0; r < 4; ++r) {           // 16 independent rcp
        iv[r] = frcp(1.f + e[r]);
        fv[r] = frcp(1.f + e[4 + r]);
        gq[r] = frcp(1.f + e[8 + r]);
        ov[r] = frcp(1.f + e[12 + r]);
    }
    float ec[4];
    #pragma unroll
    for (int r = 0; r < 4; ++r) {           // 4 scaled c-updates + exp2
        float gvs = fmaf(-2.f * TWO_LOG2E, gq[r], TWO_LOG2E);  // 2log2e*tanh(g)
        cs[r] = fmaf(fv[r], cs[r], iv[r] * gvs);
        ec[r] = fexp2(cs[r]);
    }
    f32x4 h;
    #pragma unroll
    for (int r = 0; r < 4; ++r) {           // 4 independent rcp + finish
        float th = fmaf(-2.f, frcp(1.f + ec[r]), 1.f);
        h[r] = ov[r] * th;
    }
    return h;
}

__global__ __launch_bounds__(512, 1)
void lstm_fused(const float* __restrict__ x,
                const float* __restrict__ w_ih0, const float* __restrict__ w_hh0,
                const float* __restrict__ b_ih0, const float* __restrict__ b_hh0,
                const float* __restrict__ w_ih1, const float* __restrict__ w_hh1,
                const float* __restrict__ b_ih1, const float* __restrict__ b_hh1,
                const float* __restrict__ w_lin, const float* __restrict__ b_lin,
                float* __restrict__ out)
{
    __shared__ __align__(16) short xs[16 * 512];        // 16 KB x-chunk
    __shared__ __align__(16) short h0s[2][16 * 64];     // h0 double buffer
    __shared__ __align__(16) short h1s[16 * 64];        // h1 single buffer
    __shared__ float red[4][16];

    const int tid  = threadIdx.x;
    const int w    = tid >> 6;       // wave 0..7
    const int role = w >> 2;         // 0 = layer0, 1 = layer1
    const int wl   = w & 3;          // j-slice [16wl, 16wl+16)
    const int l    = tid & 63;
    const int bcol = l & 15;
    const int q    = l >> 4;
    const int b0   = blockIdx.x * 16;

    for (int i = tid; i < 16 * 512; i += 512) xs[i] = 0;
    for (int i = tid; i < 16 * 64; i += 512) {
        h0s[0][i] = 0; h0s[1][i] = 0; h1s[i] = 0;
    }
    __syncthreads();

    // sigma(x)=rcp(1+exp2(-x*log2e)); tanh(x)=1-2*rcp(1+exp2(2x*log2e))
    const float scm[4] = { -LOG2E, -LOG2E, TWO_LOG2E, -LOG2E };

    s16x8 aW[4][4];
    f32x4 bias[4];
    #pragma unroll
    for (int m = 0; m < 4; ++m) {
        const int R = m * 64 + wl * 16 + bcol;
        const float sc = scm[m];
        if (role == 0) {
            #pragma unroll
            for (int r = 0; r < 8; ++r) {
                int k = q * 8 + r;
                aW[m][0][r] = (k < 9) ? f2bf(w_ih0[R * 9 + k] * sc) : (short)0;
            }
            #pragma unroll
            for (int kf = 0; kf < 2; ++kf) {
                const float* p = w_hh0 + R * 64 + kf * 32 + q * 8;
                #pragma unroll
                for (int r = 0; r < 8; ++r) aW[m][1 + kf][r] = f2bf(p[r] * sc);
            }
            #pragma unroll
            for (int r = 0; r < 8; ++r) aW[m][3][r] = 0;
            #pragma unroll
            for (int r = 0; r < 4; ++r) {
                int G = m * 64 + wl * 16 + q * 4 + r;
                bias[m][r] = (b_ih0[G] + b_hh0[G]) * sc;
            }
        } else {
            #pragma unroll
            for (int kf = 0; kf < 4; ++kf) {
                int ks = kf * 32 + q * 8;
                const float* p = (ks < 64) ? (w_ih1 + R * 64 + ks)
                                           : (w_hh1 + R * 64 + (ks - 64));
                #pragma unroll
                for (int r = 0; r < 8; ++r) aW[m][kf][r] = f2bf(p[r] * sc);
            }
            #pragma unroll
            for (int r = 0; r < 4; ++r) {
                int G = m * 64 + wl * 16 + q * 4 + r;
                bias[m][r] = (b_ih1[G] + b_hh1[G]) * sc;
            }
        }
    }

    f32x4 cs = {0.f, 0.f, 0.f, 0.f};     // scaled cell state c*2log2e
    f32x4 hq = {0.f, 0.f, 0.f, 0.f};
    float eR0[16];                       // role0: stage-1 outputs, A(i) -> B(i)
    float eR1[16];                       // role1: stage-1 outputs, B(i) -> A(i+1)
    #pragma unroll
    for (int k = 0; k < 16; ++k) { eR0[k] = 1.f; eR1[k] = 1.f; }

    const int hrd0 = bcol * 64 + (((q    ) ^ (bcol & 7)) << 3);
    const int hrd1 = bcol * 64 + (((4 + q) ^ (bcol & 7)) << 3);
    const int hwr  = bcol * 64 + (((wl * 2 + (q >> 1)) ^ (bcol & 7)) << 3)
                   + ((q & 1) << 2);
    const int xrd  = bcol * 32 + ((q ^ (bcol & 3)) << 3);

    const int    ld_b = (tid & 255) >> 4, ld_t = tid & 15;
    const float* xrow = x + (size_t)(b0 + ld_b) * (336 * 9) + ld_t * 9;
    const int    xs_wr_base = ld_t * 512 + ld_b * 32;
    const int    xswzw = (ld_b & 3) << 3;

    #pragma unroll 1
    for (int i = 0; i <= 337; ++i) {
        if ((i & 15) == 0 && i < 336) {
            if (tid < 256) {
                const float* xp = xrow + (size_t)i * 9;
                #pragma unroll
                for (int d = 0; d < 9; ++d)
                    xs[(xs_wr_base + d) ^ xswzw] = f2bf(xp[d]);
            }
            __syncthreads();
        }

        // ================= interval A =================
        s16x8 ba1, bb1;                 // role1's hoisted h0(i-1) frags
        if (role == 0) {
            if (i <= 335) {
                s16x8 bx = *(const s16x8*)&xs[(i & 15) * 512 + xrd];
                const short* h0r = h0s[(i & 1) ^ 1];            // h0(i-1)
                s16x8 ba = *(const s16x8*)&h0r[hrd0];
                s16x8 bb = *(const s16x8*)&h0r[hrd1];
                f32x4 acc0[4];
                #pragma unroll
                for (int m = 0; m < 4; ++m) acc0[m] = MFMA_BF16(aW[m][0], bx, bias[m], 0, 0, 0);
                #pragma unroll
                for (int m = 0; m < 4; ++m) acc0[m] = MFMA_BF16(aW[m][1], ba, acc0[m], 0, 0, 0);
                #pragma unroll
                for (int m = 0; m < 4; ++m) acc0[m] = MFMA_BF16(aW[m][2], bb, acc0[m], 0, 0, 0);
                nl_s1(acc0, eR0);                   // stage-1 in producing interval
                __builtin_amdgcn_sched_barrier(0);  // don't sink past the barrier
            }
        } else {
            if (i >= 1 && i <= 336) {   // hoist: h0(i-1) visible since B_end(i-1)
                const short* h0r = h0s[(i & 1) ^ 1];
                ba1 = *(const s16x8*)&h0r[hrd0];
                bb1 = *(const s16x8*)&h0r[hrd1];
            }
            if (i >= 2) {   // stage-2 on gates1(i-2) -> h1(i-2) (hides reads above)
                __builtin_amdgcn_s_setprio(1);
                hq = nl_s2(eR1, cs);
                __builtin_amdgcn_s_setprio(0);
                *(s16x4*)&h1s[hwr] = pack_bf16x4(hq[0], hq[1], hq[2], hq[3]);
            }
        }
        __syncthreads();   // B_mid: h1(i-2) visible

        // ================= interval B =================
        if (role == 0) {
            if (i <= 335) {
                __builtin_amdgcn_s_setprio(1);
                hq = nl_s2(eR0, cs);                // stage-2 -> h0(i)
                __builtin_amdgcn_s_setprio(0);
                short* h0w = h0s[i & 1];
                *(s16x4*)&h0w[hwr] = pack_bf16x4(hq[0], hq[1], hq[2], hq[3]);
            }
        } else {
            if (i >= 1 && i <= 336) {   // gates1(i-1) from h0(i-1), h1(i-2)
                s16x8 b1a = *(const s16x8*)&h1s[hrd0];
                s16x8 b1b = *(const s16x8*)&h1s[hrd1];
                f32x4 accL1[4];
                #pragma unroll
                for (int m = 0; m < 4; ++m) accL1[m] = MFMA_BF16(aW[m][0], ba1, bias[m], 0, 0, 0);
                #pragma unroll
                for (int m = 0; m < 4; ++m) accL1[m] = MFMA_BF16(aW[m][1], bb1, accL1[m], 0, 0, 0);
                #pragma unroll
                for (int m = 0; m < 4; ++m) accL1[m] = MFMA_BF16(aW[m][2], b1a, accL1[m], 0, 0, 0);
                #pragma unroll
                for (int m = 0; m < 4; ++m) accL1[m] = MFMA_BF16(aW[m][3], b1b, accL1[m], 0, 0, 0);
                nl_s1(accL1, eR1);                  // stage-1 in producing interval
                __builtin_amdgcn_sched_barrier(0);
            }
        }
        __syncthreads();   // B_end: h0(i) visible
    }

    // ---- out[b] = sigm(sum_j h1_335[b][j] * w_lin[j] + b_lin) ----
    if (role == 1) {
        float part = hq[0] * w_lin[wl * 16 + q * 4 + 0]
                   + hq[1] * w_lin[wl * 16 + q * 4 + 1]
                   + hq[2] * w_lin[wl * 16 + q * 4 + 2]
                   + hq[3] * w_lin[wl * 16 + q * 4 + 3];
        part += __shfl_xor(part, 16, 64);
        part += __shfl_xor(part, 32, 64);
        if (q == 0) red[wl][bcol] = part;
    }
    __syncthreads();
    if (tid < 16) {
        float s = red[0][tid] + red[1][tid] + red[2][tid] + red[3][tid] + b_lin[0];
        out[b0 + tid] = rcp1p2(-s * LOG2E);
    }
}

extern "C" void kernel_launch(void* const* d_in, const int* in_sizes, int n_in,
                              void* d_out, int out_size, void* d_ws, size_t ws_size,
                              hipStream_t stream) {
    const float* x     = (const float*)d_in[0];
    const float* w_ih0 = (const float*)d_in[1];
    const float* w_hh0 = (const float*)d_in[2];
    const float* b_ih0 = (const float*)d_in[3];
    const float* b_hh0 = (const float*)d_in[4];
    const float* w_ih1 = (const float*)d_in[5];
    const float* w_hh1 = (const float*)d_in[6];
    const float* b_ih1 = (const float*)d_in[7];
    const float* b_hh1 = (const float*)d_in[8];
    const float* w_lin = (const float*)d_in[9];
    const float* b_lin = (const float*)d_in[10];

    lstm_fused<<<dim3(256), dim3(512), 0, stream>>>(
        x, w_ih0, w_hh0, b_ih0, b_hh0,
        w_ih1, w_hh1, b_ih1, b_hh1,
        w_lin, b_lin, (float*)d_out);
}